// Round 2
// baseline (2687.290 us; speedup 1.0000x reference)
//
#include <hip/hip_runtime.h>
#include <hip/hip_bf16.h>

#define N 8192
#define NW 128           // 64-bit mask words per row
#define MAXP 1000
typedef unsigned long long u64;

// Static device globals (avoids relying on ws_size). ~8.3 MB total.
__device__ u64    g_key[N];
__device__ float4 g_sboxes[N];
__device__ float  g_sscores[N];
__device__ u64    g_mask[(size_t)N * NW];   // 8 MB suppression bitmask
__device__ u64    g_keep[NW];
__device__ int    g_wpre[NW];

// ---- K1: sortable keys. score bits are monotonic for non-negative floats;
// ~bits gives descending score; low 32 = index gives the stable tie-break
// matching jnp.argsort(-scores).
__global__ __launch_bounds__(256) void k_key(const float* __restrict__ scores) {
  int i = blockIdx.x * 256 + threadIdx.x;
  unsigned sb = __float_as_uint(scores[i]);
  g_key[i] = ((u64)(sb ^ 0xFFFFFFFFu) << 32) | (unsigned)i;
}

// ---- K2: O(N^2) rank sort; keys are distinct so ranks form a permutation.
__global__ __launch_bounds__(256) void k_rank(const float4* __restrict__ boxes,
                                              const float* __restrict__ scores) {
  int i = blockIdx.x * 256 + threadIdx.x;
  u64 ki = g_key[i];
  int cnt = 0;
  for (int t = 0; t < N; ++t) cnt += (g_key[t] < ki) ? 1 : 0;
  g_sboxes[cnt] = boxes[i];
  g_sscores[cnt] = scores[i];
}

// ---- K3: 64x64 IoU bit tiles. Bit c of word (i, col) set iff j=col*64+c > i
// and iou(i,j) > 0.5. fp contract OFF so rounding matches numpy exactly.
__global__ __launch_bounds__(64) void k_mask() {
#pragma clang fp contract(off)
  const int col = blockIdx.x, row = blockIdx.y;
  const int t = threadIdx.x;
  const int i = row * 64 + t;
  if (col < row) { g_mask[(size_t)i * NW + col] = 0ull; return; }
  __shared__ float4 cb[64];
  cb[t] = g_sboxes[col * 64 + t];
  __syncthreads();
  float4 bi = g_sboxes[i];
  float areai = (bi.z - bi.x) * (bi.w - bi.y);
  u64 bits = 0;
  for (int c = 0; c < 64; ++c) {
    int j = col * 64 + c;
    if (j <= i) continue;
    float4 bj = cb[c];
    float xx1 = fmaxf(bi.x, bj.x);
    float yy1 = fmaxf(bi.y, bj.y);
    float xx2 = fminf(bi.z, bj.z);
    float yy2 = fminf(bi.w, bj.w);
    float ww = fmaxf(xx2 - xx1, 0.0f);
    float hh = fmaxf(yy2 - yy1, 0.0f);
    float inter = ww * hh;
    float areaj = (bj.z - bj.x) * (bj.w - bj.y);
    float uni = (areai + areaj) - inter;
    float iou = inter / uni;
    if (iou > 0.5f) bits |= (1ull << c);
  }
  g_mask[(size_t)i * NW + col] = bits;
}

// ---- K4: sequential greedy scan, one wave. Lane l owns remv words 2l,2l+1.
// The current group's word is tracked uniformly (redundant uniform load of
// mask[i][g]) so the per-row critical path has no cross-lane op. Rows are
// prefetched in chunks of 8 (double-buffered), lower-triangle words skipped.
#define CH 8

#define LOADC(m0, m1, mw, chunk)                                         \
  do {                                                                   \
    const int i0_ = (chunk) * CH;                                        \
    const int g_ = i0_ >> 6;                                             \
    const bool ld_ = (2 * lane + 1) >= g_;                               \
    const u64* base_ = g_mask + (size_t)i0_ * NW;                        \
    _Pragma("unroll")                                                    \
    for (int p = 0; p < CH; ++p) {                                       \
      if (ld_) {                                                         \
        m0[p] = base_[(size_t)p * NW + 2 * lane];                        \
        m1[p] = base_[(size_t)p * NW + 2 * lane + 1];                    \
      }                                                                  \
      mw[p] = base_[(size_t)p * NW + g_];                                \
    }                                                                    \
  } while (0)

#define PROCC(m0, m1, mw, chunk)                                         \
  do {                                                                   \
    const int i0_ = (chunk) * CH;                                        \
    const int g_ = i0_ >> 6;                                             \
    if ((i0_ & 63) == 0) {                                               \
      u64 wv_ = (g_ & 1) ? r1 : r0;                                      \
      w = __shfl(wv_, g_ >> 1);                                          \
    }                                                                    \
    const bool lact_ = (2 * lane + 1) >= g_;                             \
    _Pragma("unroll")                                                    \
    for (int p = 0; p < CH; ++p) {                                       \
      const int b_ = (i0_ + p) & 63;                                     \
      const bool alive_ = ((w >> b_) & 1ull) == 0ull;                    \
      if (alive_) {                                                      \
        w |= mw[p];                                                      \
        if (lact_) { r0 |= m0[p]; r1 |= m1[p]; }                         \
      }                                                                  \
    }                                                                    \
  } while (0)

__global__ __launch_bounds__(64) void k_serial() {
  const int lane = threadIdx.x;
  u64 r0 = 0, r1 = 0;     // suppression words 2*lane, 2*lane+1
  u64 w = 0;              // current group's remv word (wave-uniform value)
  u64 a0[CH], a1[CH], aw[CH];
  u64 b0[CH], b1[CH], bw[CH];

  LOADC(a0, a1, aw, 0);
  const int NCH = N / CH;  // 1024
  for (int c = 0; c < NCH; c += 2) {
    LOADC(b0, b1, bw, c + 1);
    PROCC(a0, a1, aw, c);
    if (c + 2 < NCH) LOADC(a0, a1, aw, c + 2);
    PROCC(b0, b1, bw, c + 1);
  }

  // keep words + exclusive popcount prefix (wave scan)
  u64 k0 = ~r0, k1 = ~r1;
  g_keep[2 * lane] = k0;
  g_keep[2 * lane + 1] = k1;
  int pc0 = __popcll(k0);
  int s = pc0 + __popcll(k1);
  int ex = s;
  for (int d = 1; d < 64; d <<= 1) {
    int t2 = __shfl_up(ex, d);
    if (lane >= d) ex += t2;
  }
  ex -= s;  // exclusive prefix of kept count before word 2*lane
  g_wpre[2 * lane] = ex;
  g_wpre[2 * lane + 1] = ex + pc0;
}

// ---- K5: apply max-proposals cap and write masked rows.
__global__ __launch_bounds__(256) void k_out(float* __restrict__ out) {
  int i = blockIdx.x * 256 + threadIdx.x;
  int w = i >> 6, b = i & 63;
  u64 kw = g_keep[w];
  int before = g_wpre[w] + (b ? __popcll(kw << (64 - b)) : 0);
  bool k = (((kw >> b) & 1ull) != 0ull) && (before < MAXP);
  float m = k ? 1.0f : 0.0f;
  float4 bx = g_sboxes[i];
  float sc = g_sscores[i];
  out[i * 5 + 0] = bx.x * m;
  out[i * 5 + 1] = bx.y * m;
  out[i * 5 + 2] = bx.z * m;
  out[i * 5 + 3] = bx.w * m;
  out[i * 5 + 4] = sc * m;
}

extern "C" void kernel_launch(void* const* d_in, const int* in_sizes, int n_in,
                              void* d_out, int out_size, void* d_ws, size_t ws_size,
                              hipStream_t stream) {
  const float4* boxes = (const float4*)d_in[0];
  const float*  scores = (const float*)d_in[1];
  float* out = (float*)d_out;

  hipLaunchKernelGGL(k_key,    dim3(N / 256), dim3(256), 0, stream, scores);
  hipLaunchKernelGGL(k_rank,   dim3(N / 256), dim3(256), 0, stream, boxes, scores);
  hipLaunchKernelGGL(k_mask,   dim3(NW, NW),  dim3(64),  0, stream);
  hipLaunchKernelGGL(k_serial, dim3(1),       dim3(64),  0, stream);
  hipLaunchKernelGGL(k_out,    dim3(N / 256), dim3(256), 0, stream, out);
}

// Round 3
// 755.361 us; speedup vs baseline: 3.5576x; 3.5576x over previous
//
#include <hip/hip_runtime.h>
#include <hip/hip_bf16.h>

#define N 8192
#define NW 128           // 64-bit mask words per row
#define GR 64            // rows per group
#define GROUPS 128
#define MAXP 1000
typedef unsigned long long u64;

// Static device globals (avoids relying on ws_size). ~8.3 MB total.
__device__ u64    g_key[N];
__device__ float4 g_sboxes[N];
__device__ float  g_sscores[N];
__device__ u64    g_mask[(size_t)N * NW];   // 8 MB suppression bitmask (upper-tri blocks only valid)
__device__ u64    g_keep[NW];
__device__ int    g_wpre[NW];

// ---- K1: sortable keys. score bits are monotonic for non-negative floats;
// ~bits gives descending score; low 32 = index gives the stable tie-break
// matching jnp.argsort(-scores).
__global__ __launch_bounds__(256) void k_key(const float* __restrict__ scores) {
  int i = blockIdx.x * 256 + threadIdx.x;
  unsigned sb = __float_as_uint(scores[i]);
  g_key[i] = ((u64)(sb ^ 0xFFFFFFFFu) << 32) | (unsigned)i;
}

// ---- K2: O(N^2) rank sort; keys are distinct so ranks form a permutation.
__global__ __launch_bounds__(256) void k_rank(const float4* __restrict__ boxes,
                                              const float* __restrict__ scores) {
  int i = blockIdx.x * 256 + threadIdx.x;
  u64 ki = g_key[i];
  int cnt = 0;
  for (int t = 0; t < N; ++t) cnt += (g_key[t] < ki) ? 1 : 0;
  g_sboxes[cnt] = boxes[i];
  g_sscores[cnt] = scores[i];
}

// ---- K3: 64x64 IoU bit tiles, upper-triangle blocks only (col >= row).
// Bit c of word (i, col) set iff j=col*64+c > i and iou(i,j) > 0.5.
// fp contract OFF so rounding matches numpy exactly.
__global__ __launch_bounds__(64) void k_mask() {
#pragma clang fp contract(off)
  const int col = blockIdx.x, row = blockIdx.y;
  const int t = threadIdx.x;
  if (col < row) return;  // never read by k_serial2
  const int i = row * 64 + t;
  __shared__ float4 cb[64];
  cb[t] = g_sboxes[col * 64 + t];
  __syncthreads();
  float4 bi = g_sboxes[i];
  float areai = (bi.z - bi.x) * (bi.w - bi.y);
  u64 bits = 0;
  for (int c = 0; c < 64; ++c) {
    int j = col * 64 + c;
    if (j <= i) continue;
    float4 bj = cb[c];
    float xx1 = fmaxf(bi.x, bj.x);
    float yy1 = fmaxf(bi.y, bj.y);
    float xx2 = fminf(bi.z, bj.z);
    float yy2 = fminf(bi.w, bj.w);
    float ww = fmaxf(xx2 - xx1, 0.0f);
    float hh = fmaxf(yy2 - yy1, 0.0f);
    float inter = ww * hh;
    float areaj = (bj.z - bj.x) * (bj.w - bj.y);
    float uni = (areai + areaj) - inter;
    float iou = inter / uni;
    if (iou > 0.5f) bits |= (1ull << c);
  }
  g_mask[(size_t)i * NW + col] = bits;
}

__device__ inline u64 shflxor64(u64 v, int m) {
  unsigned lo = (unsigned)v, hi = (unsigned)(v >> 32);
  lo = __shfl_xor(lo, m);
  hi = __shfl_xor(hi, m);
  return ((u64)hi << 32) | lo;
}

// ---- K4: group-pipelined greedy scan. 16 waves stream mask rows through a
// double-buffered LDS tile; wave 0 makes the serial keep decisions (cost ~
// 15 cycles per KEPT box via ffs+readlane); all 1024 threads apply kept rows'
// suppression words to the LDS-resident remv[128].
__global__ __launch_bounds__(1024) void k_serial2() {
  const int t = threadIdx.x;
  const int r = t >> 4;        // row within group (0..63)
  const int c0 = t & 15;       // word-lane (0..15)
  const int wave = t >> 6;
  const int lane = t & 63;

  __shared__ u64 buf[2][GR][NW];   // 128 KB double buffer
  __shared__ u64 remv[NW];
  __shared__ u64 keep_arr[NW];

  if (t < NW) { remv[t] = 0; keep_arr[t] = 0; }

  u64 regs[8];
  // load group 0 (all words: w >= 0)
#pragma unroll
  for (int k = 0; k < 8; ++k) {
    int w = c0 + 16 * k;
    regs[k] = g_mask[(size_t)r * NW + w];
  }
  __syncthreads();
  // stage group 0, load group 1
#pragma unroll
  for (int k = 0; k < 8; ++k) buf[0][r][c0 + 16 * k] = regs[k];
#pragma unroll
  for (int k = 0; k < 8; ++k) {
    int w = c0 + 16 * k;
    regs[k] = (w >= 1) ? g_mask[(size_t)(GR + r) * NW + w] : 0ull;
  }
  __syncthreads();

  int p = 0;
  for (int g = 0; g < GROUPS; ++g) {
    // invariant: buf[p] holds group g; regs hold group g+1 (arrived or in flight)
    if (g + 1 < GROUPS) {
#pragma unroll
      for (int k = 0; k < 8; ++k) buf[p ^ 1][r][c0 + 16 * k] = regs[k];
    }
    if (g + 2 < GROUPS) {
#pragma unroll
      for (int k = 0; k < 8; ++k) {
        int w = c0 + 16 * k;
        regs[k] = (w >= g + 2) ? g_mask[(size_t)((g + 2) * GR + r) * NW + w] : 0ull;
      }
    }
    if (wave == 0) {
      // phase 1: serial within-group decisions (uniform scalar loop)
      u64 mrow = buf[p][lane][g];    // group-diagonal word of row (lane)
      u64 pending = ~remv[g];
      u64 keepm = 0;
      while (pending) {
        int rr = __ffsll((long long)pending) - 1;
        keepm |= (1ull << rr);
        pending &= pending - 1;
        unsigned lo = (unsigned)mrow, hi = (unsigned)(mrow >> 32);
        u64 sup = ((u64)__builtin_amdgcn_readlane(hi, rr) << 32) |
                  (u64)__builtin_amdgcn_readlane(lo, rr);
        pending &= ~sup;
      }
      if (lane == 0) keep_arr[g] = keepm;
    }
    __syncthreads();
    // phase 2: OR kept rows into remv for words > g (8 threads per word)
    {
      int w = g + 1 + (t >> 3);
      u64 val = 0;
      int kk = t & 7;
      if (w < NW) {
        u64 stripe = keep_arr[g] & (0x0101010101010101ull << kk);
        while (stripe) {
          int rr = __ffsll((long long)stripe) - 1;
          stripe &= stripe - 1;
          val |= buf[p][rr][w];
        }
      }
      val |= shflxor64(val, 1);
      val |= shflxor64(val, 2);
      val |= shflxor64(val, 4);
      if (w < NW && kk == 0) remv[w] |= val;
    }
    __syncthreads();
    p ^= 1;
  }

  // epilogue: keep words + exclusive popcount prefix (wave 0)
  if (wave == 0) {
    u64 k0 = keep_arr[2 * lane];
    u64 k1 = keep_arr[2 * lane + 1];
    g_keep[2 * lane] = k0;
    g_keep[2 * lane + 1] = k1;
    int pc0 = __popcll(k0);
    int s = pc0 + __popcll(k1);
    int ex = s;
    for (int d = 1; d < 64; d <<= 1) {
      int t2 = __shfl_up(ex, d);
      if (lane >= d) ex += t2;
    }
    ex -= s;
    g_wpre[2 * lane] = ex;
    g_wpre[2 * lane + 1] = ex + pc0;
  }
}

// ---- K5: apply max-proposals cap and write masked rows.
__global__ __launch_bounds__(256) void k_out(float* __restrict__ out) {
  int i = blockIdx.x * 256 + threadIdx.x;
  int w = i >> 6, b = i & 63;
  u64 kw = g_keep[w];
  int before = g_wpre[w] + (b ? __popcll(kw << (64 - b)) : 0);
  bool k = (((kw >> b) & 1ull) != 0ull) && (before < MAXP);
  float m = k ? 1.0f : 0.0f;
  float4 bx = g_sboxes[i];
  float sc = g_sscores[i];
  out[i * 5 + 0] = bx.x * m;
  out[i * 5 + 1] = bx.y * m;
  out[i * 5 + 2] = bx.z * m;
  out[i * 5 + 3] = bx.w * m;
  out[i * 5 + 4] = sc * m;
}

extern "C" void kernel_launch(void* const* d_in, const int* in_sizes, int n_in,
                              void* d_out, int out_size, void* d_ws, size_t ws_size,
                              hipStream_t stream) {
  const float4* boxes = (const float4*)d_in[0];
  const float*  scores = (const float*)d_in[1];
  float* out = (float*)d_out;

  hipLaunchKernelGGL(k_key,     dim3(N / 256), dim3(256),  0, stream, scores);
  hipLaunchKernelGGL(k_rank,    dim3(N / 256), dim3(256),  0, stream, boxes, scores);
  hipLaunchKernelGGL(k_mask,    dim3(NW, NW),  dim3(64),   0, stream);
  hipLaunchKernelGGL(k_serial2, dim3(1),       dim3(1024), 0, stream);
  hipLaunchKernelGGL(k_out,     dim3(N / 256), dim3(256),  0, stream, out);
}